// Round 11
// baseline (219.980 us; speedup 1.0000x reference)
//
#include <hip/hip_runtime.h>
#include <stdint.h>

typedef _Float16 half_t;
typedef __attribute__((ext_vector_type(8))) _Float16 half8;
typedef __attribute__((ext_vector_type(4))) _Float16 half4;
typedef __attribute__((ext_vector_type(4))) float floatx4;
typedef __attribute__((ext_vector_type(2))) uint32_t uint32x2;

#define SEQ 2048
#define NH 16
#define HD 64

#define MFMA16(a, b, c) __builtin_amdgcn_mfma_f32_16x16x16f16(a, b, c, 0, 0, 0)
#define MFMA32K(a, b, c) __builtin_amdgcn_mfma_f32_16x16x32_f16(a, b, c, 0, 0, 0)

// SCALE * log2(e): scores exit QK in log2 domain -> raw v_exp_f32
#define QSCALE 0.1803368801111306f

// ---------------- prep: casts + weight transposes + mask tables -------------
__global__ __launch_bounds__(256) void prep(
    const float* __restrict__ query, const float* __restrict__ key_value,
    const float* __restrict__ Wq, const float* __restrict__ Wkv,
    const float* __restrict__ Wo, half_t* __restrict__ xq,
    half_t* __restrict__ xkv, half_t* __restrict__ wqT,
    half_t* __restrict__ wkvT, half_t* __restrict__ woT,
    uint8_t* __restrict__ tok, uint8_t* __restrict__ tok16,
    uint64_t* __restrict__ maskw) {
  int bx = blockIdx.x, tid = threadIdx.x;
  if (bx < 2048) {  // fp32 -> f16 casts, 4096 elements per block
    const float* s; half_t* d; int base;
    if (bx < 1024) { s = query; d = xq; base = bx * 4096; }
    else { s = key_value; d = xkv; base = (bx - 1024) * 4096; }
#pragma unroll
    for (int u = 0; u < 4; ++u) {
      int i = base + u * 1024 + tid * 4;
      floatx4 v = *(const floatx4*)(s + i);
      half4 h;
      h[0] = (half_t)v[0]; h[1] = (half_t)v[1];
      h[2] = (half_t)v[2]; h[3] = (half_t)v[3];
      *(half4*)(d + i) = h;
    }
    return;
  }
  if (bx < 4096) {  // weight transpose+cast, 2 tiles per block
    __shared__ float tile[32][33];
    int tx = tid & 31, ty = tid >> 5;
    const int K = 1024;
#pragma unroll
    for (int u = 0; u < 2; ++u) {
      int t = (bx - 2048) * 2 + u;
      const float* W; half_t* Wt; int N, nt, kt;
      if (t < 1024) { W = Wq; Wt = wqT; N = 1024; nt = t & 31; kt = t >> 5; }
      else if (t < 3072) { int t2 = t - 1024; W = Wkv; Wt = wkvT; N = 2048; nt = t2 & 63; kt = t2 >> 6; }
      else { int t2 = t - 3072; W = Wo; Wt = woT; N = 1024; nt = t2 & 31; kt = t2 >> 5; }
      int n0 = nt * 32, k0 = kt * 32;
#pragma unroll
      for (int i = 0; i < 4; ++i)
        tile[ty + i * 8][tx] = W[(size_t)(k0 + ty + i * 8) * N + n0 + tx];
      __syncthreads();
#pragma unroll
      for (int i = 0; i < 4; ++i)
        Wt[(size_t)(n0 + ty + i * 8) * K + k0 + tx] = (half_t)tile[tx][ty + i * 8];
      __syncthreads();
    }
    return;
  }
  // mask tables
  __shared__ uint8_t slut[2048];
  int ib = bx - 4096;
  for (int d = tid; d < 2048; d += 256) {
    int x = d;
    bool ok = true;
    for (int it = 0; it < 7; ++it) { ok &= ((x % 3) != 1); x /= 3; }
    ok &= (x == 0);
    slut[d] = (ok || d <= 64) ? 1 : 0;
  }
  __syncthreads();
  if (ib == 0) {
    if (tid < 64) {  // 64-gran tile activity
      int delta = tid - 32;
      int lo = delta * 64 - 63, hi = delta * 64 + 63;
      uint8_t any = 0;
      for (int x = lo; x <= hi; ++x) {
        int a = x < 0 ? -x : x;
        if (a < 2048) any |= slut[a];
      }
      tok[tid] = any;
    }
    {  // 16-gran subtile activity
      int d16 = tid - 128;
      int ctr = d16 * 16;
      uint8_t any = 0;
      for (int x = ctr - 15; x <= ctr + 15; ++x) {
        int a = x < 0 ? -x : x;
        if (a < 2048) any |= slut[a];
      }
      tok16[tid] = any;
    }
  }
  int g = ib * 256 + tid;  // 0..4095
  int tt = g - 2048;
  uint64_t w = 0;
  for (int jj = 0; jj < 64; ++jj) {
    int d = tt - jj; d = d < 0 ? -d : d;
    if (d < 2048 && slut[d]) w |= (1ull << jj);
  }
  maskw[g] = w;
}

// ---------------- async global->LDS 16B -------------------------------------
__device__ __forceinline__ void cp16(half_t* lds, const half_t* g) {
  __builtin_amdgcn_global_load_lds(
      (const __attribute__((address_space(1))) uint32_t*)g,
      (__attribute__((address_space(3))) uint32_t*)lds, 16, 0, 0);
}

// ---------------- fused q+kv projection GEMM: 256x256 8-phase (T2+T3+T4+T5) -
// Template per docs §5 (m201): BM=BN=256, BK=64, 8 waves, 128 KiB LDS
// (2 dbuf x 2 half x 128x64 x {A,B}).
// Wave tiling is INTERLEAVED so each phase needs exactly one A-half (mq) and
// one B-half (nq) for ALL waves: wave w covers rows {mq*128 + (w>>2)*64 +
// i*16} and cols {nq*128 + (w&3)*32 + j*16} across phases (mq,nq).
// st_16x32 swizzle (byte ^= ((byte>>9)&1)<<5 == halfcol ^= ((row>>2)&1)<<4):
// applied on the pre-swizzled GLOBAL source (rule 21: DMA dest is linear)
// and on the ds_read side.
// Counted vmcnt (FIFO retirement math): stage order per K-tile = A0,B0,B1,A1
// at phases 0..3. Phase needs: p0:{A0,B0} p1:{+B1} p2:{+A1} p3:{}. With one
// half-tile (2 loads/thread) staged per phase, waiting vmcnt(4) at p0/p1/p2
// retires everything but the 2 newest half-tiles => the needed ones are done,
// 4-6 loads always in flight. Last K-tile (no staging): vmcnt(4)/(2)/(0).
#define VMC(n) asm volatile("s_waitcnt vmcnt(" #n ")" ::: "memory")

#define STG_A(kt2, mh)                                                        \
  {                                                                           \
    half_t* d_ = &As[(((kt2) & 1) * 2 + (mh)) * 8192 + wave * 512];           \
    const half_t* s_ = A + (size_t)(m0 + (mh) * 128 + r1) * K + (kt2) * 64 + hsw; \
    cp16(d_, s_);                                                             \
    cp16(d_ + 4096, s_ + (size_t)64 * K);                                     \
  }
#define STG_B(kt2, nh)                                                        \
  {                                                                           \
    half_t* d_ = &Bs[(((kt2) & 1) * 2 + (nh)) * 8192 + wave * 512];           \
    const half_t* s_ = Bt + (size_t)(n0 + (nh) * 128 + r1) * K + (kt2) * 64 + hsw; \
    cp16(d_, s_);                                                             \
    cp16(d_ + 4096, s_ + (size_t)64 * K);                                     \
  }

#define PHASE(KB, MQ, NQ, ...)                                                \
  do {                                                                        \
    __builtin_amdgcn_s_barrier();                                             \
    __builtin_amdgcn_sched_barrier(0);                                        \
    const half_t* Ab = &As[((KB) * 2 + (MQ)) * 8192];                         \
    const half_t* Bb = &Bs[((KB) * 2 + (NQ)) * 8192];                         \
    half8 af[4][2], bf[2][2];                                                 \
    _Pragma("unroll") for (int i_ = 0; i_ < 4; ++i_) {                        \
      int rl_ = mw * 64 + i_ * 16 + c;                                        \
      af[i_][0] = *(const half8*)&Ab[rl_ * 64 + ((quad * 8) ^ rsw)];          \
      af[i_][1] = *(const half8*)&Ab[rl_ * 64 + ((32 + quad * 8) ^ rsw)];     \
    }                                                                         \
    _Pragma("unroll") for (int j_ = 0; j_ < 2; ++j_) {                        \
      int cl_ = nw * 32 + j_ * 16 + c;                                        \
      bf[j_][0] = *(const half8*)&Bb[cl_ * 64 + ((quad * 8) ^ rsw)];          \
      bf[j_][1] = *(const half8*)&Bb[cl_ * 64 + ((32 + quad * 8) ^ rsw)];     \
    }                                                                         \
    __VA_ARGS__;                                                              \
    __builtin_amdgcn_sched_barrier(0);                                        \
    __builtin_amdgcn_s_barrier();                                             \
    __builtin_amdgcn_s_setprio(1);                                            \
    _Pragma("unroll") for (int i_ = 0; i_ < 4; ++i_)                          \
      _Pragma("unroll") for (int j_ = 0; j_ < 2; ++j_) {                      \
        acc[MQ][NQ][i_][j_] = MFMA32K(af[i_][0], bf[j_][0], acc[MQ][NQ][i_][j_]); \
        acc[MQ][NQ][i_][j_] = MFMA32K(af[i_][1], bf[j_][1], acc[MQ][NQ][i_][j_]); \
      }                                                                       \
    __builtin_amdgcn_s_setprio(0);                                            \
  } while (0)

__global__ __launch_bounds__(512, 1) void gemm_qkv(
    const half_t* __restrict__ xq, const half_t* __restrict__ xkv,
    const half_t* __restrict__ wqT, const half_t* __restrict__ wkvT,
    const float* __restrict__ bq, const float* __restrict__ bkv,
    half_t* __restrict__ qout, half_t* __restrict__ kout,
    half_t* __restrict__ vTout) {
  extern __shared__ char smemraw[];
  half_t* As = (half_t*)smemraw;  // [2 buf][2 half][128*64] = 64 KB
  half_t* Bs = As + 32768;        // same = 64 KB
  const int K = 1024, NT = 16;
  bool isq = blockIdx.y < 4;
  const half_t* A = isq ? xq : xkv;
  const half_t* Bt = isq ? wqT : wkvT;
  const float* bias = isq ? bq : bkv;
  int n0 = (isq ? blockIdx.y : (blockIdx.y - 4)) * 256;
  int m0 = blockIdx.x * 256;

  int tid = threadIdx.x;
  int wave = tid >> 6, lane = tid & 63;
  int c = lane & 15, quad = lane >> 4;
  int mw = wave >> 2, nw = wave & 3;

  floatx4 acc[2][2][4][2] = {};

  // staging geometry: thread covers dest rows r1, r1+64 of a 128x64 half-tile
  int r1 = tid >> 3;                   // 0..63 (= wave*8 + lane>>3)
  int hh = (tid & 7) * 8;              // dest half-col (lane*16B linear)
  int hsw = hh ^ (((r1 >> 2) & 1) << 4);  // pre-swizzled SOURCE col; (r1+64) same parity
  int rsw = ((c >> 2) & 1) << 4;       // read-side swizzle bit ((row>>2)&1 == (c>>2)&1)

  // prologue: K-tile 0 fully staged (8 loads in flight)
  STG_A(0, 0); STG_B(0, 0); STG_B(0, 1); STG_A(0, 1);

  for (int kt = 0; kt + 1 < NT; ++kt) {
    int kb = kt & 1, kn = kt + 1;
    VMC(4); PHASE(kb, 0, 0, STG_A(kn, 0));
    VMC(4); PHASE(kb, 0, 1, STG_B(kn, 0));
    VMC(4); PHASE(kb, 1, 0, STG_B(kn, 1));
            PHASE(kb, 1, 1, STG_A(kn, 1));
  }
  {  // peeled last K-tile: no staging, drain counted
    int kb = (NT - 1) & 1;
    VMC(4); PHASE(kb, 0, 0, (void)0);
    VMC(2); PHASE(kb, 0, 1, (void)0);
    VMC(0); PHASE(kb, 1, 0, (void)0);
            PHASE(kb, 1, 1, (void)0);
  }

  __syncthreads();
  half_t* ep = (half_t*)smemraw;
  int bb = m0 >> 11, sbase = m0 & 2047;
  bool isv = (!isq) && (n0 >= 1024);

  if (!isv) {  // q or k: two 128-col rounds, ep[m][cl] stride 132 -> [bh][s][d]
    half_t* outp = isq ? qout : kout;
#pragma unroll
    for (int nq = 0; nq < 2; ++nq) {
      if (nq) __syncthreads();
#pragma unroll
      for (int mq = 0; mq < 2; ++mq)
#pragma unroll
        for (int i = 0; i < 4; ++i)
#pragma unroll
          for (int j = 0; j < 2; ++j) {
            int row = mq * 128 + mw * 64 + i * 16 + quad * 4;
            int cl = nw * 32 + j * 16 + c;
            float bv = bias[n0 + nq * 128 + cl];
#pragma unroll
            for (int r = 0; r < 4; ++r) {
              float v = acc[mq][nq][i][j][r] + bv;
              if (isq) v *= QSCALE;
              ep[(row + r) * 132 + cl] = (half_t)v;
            }
          }
      __syncthreads();
#pragma unroll
      for (int rd = 0; rd < 8; ++rd) {
        int id = rd * 512 + tid;  // 256 rows x 16 chunks of 16B
        int ml = id >> 4, ch = id & 15;
        int ng = n0 + nq * 128 + ch * 8;
        int h = ng >> 6, d0 = ng & 63;
        half8 v = *(const half8*)&ep[ml * 132 + ch * 8];
        *(half8*)(outp + ((size_t)(bb * 16 + h) * SEQ + sbase + ml) * 64 + d0) = v;
      }
    }
  } else {  // v: two 128-col rounds, ep[cl][m] stride 264 -> [bh][d][s]
#pragma unroll
    for (int nq = 0; nq < 2; ++nq) {
      if (nq) __syncthreads();
#pragma unroll
      for (int mq = 0; mq < 2; ++mq)
#pragma unroll
        for (int i = 0; i < 4; ++i)
#pragma unroll
          for (int j = 0; j < 2; ++j) {
            int row = mq * 128 + mw * 64 + i * 16 + quad * 4;
            int cl = nw * 32 + j * 16 + c;
            float bv = bias[n0 + nq * 128 + cl];
            half4 hv;
#pragma unroll
            for (int r = 0; r < 4; ++r) hv[r] = (half_t)(acc[mq][nq][i][j][r] + bv);
            *(half4*)&ep[cl * 264 + row] = hv;
          }
      __syncthreads();
#pragma unroll
      for (int rd = 0; rd < 8; ++rd) {
        int id = rd * 512 + tid;  // 128 d x 32 chunks of 16B (m)
        int dl = id >> 5, mc = id & 31;
        int ng = n0 + nq * 128 + dl;
        int h = (ng >> 6) & 15, d = ng & 63;
        half8 v = *(const half8*)&ep[dl * 264 + mc * 8];
        *(half8*)(vTout + ((size_t)(bb * 16 + h) * 64 + d) * SEQ + sbase + mc * 8) = v;
      }
    }
  }
}
#undef PHASE
#undef STG_A
#undef STG_B

// ---------------- out-projection GEMM: counted vmcnt, 3-buf (r8 pattern) ----
__global__ __launch_bounds__(256) void gemm_out(
    const half_t* __restrict__ A, const half_t* __restrict__ Bt,
    const float* __restrict__ bias, float* __restrict__ outf) {
  __shared__ half_t As[3][128 * 32];
  __shared__ half_t Bs[3][64 * 32];
  const int K = 1024;
  int tid = threadIdx.x;
  int wave = tid >> 6, lane = tid & 63;
  int c = lane & 15, quad = lane >> 4;
  int wm = (wave >> 1) * 64, wn = (wave & 1) * 32;
  int m0 = blockIdx.x * 128, n0 = blockIdx.y * 64;

  floatx4 acc[4][2] = {};
  int arow = tid >> 2;
  int akc = ((tid & 3) ^ (arow & 3)) * 8;  // pre-swizzled source chunk
  int csw = c & 3;

#define OUT_ISSUE(kt2)                                                        \
  {                                                                           \
    int s_ = (kt2) % 3;                                                       \
    int k0_ = (kt2) * 32;                                                     \
    cp16(&As[s_][wave * 512], A + (size_t)(m0 + arow) * K + k0_ + akc);       \
    cp16(&As[s_][2048 + wave * 512], A + (size_t)(m0 + 64 + arow) * K + k0_ + akc); \
    cp16(&Bs[s_][wave * 512], Bt + (size_t)(n0 + arow) * K + k0_ + akc);      \
  }

  OUT_ISSUE(0)
  OUT_ISSUE(1)

  for (int kt = 0; kt < 32; ++kt) {
    if (kt < 31) {
      asm volatile("s_waitcnt vmcnt(3)" ::: "memory");
    } else {
      asm volatile("s_waitcnt vmcnt(0)" ::: "memory");
    }
    __builtin_amdgcn_s_barrier();
    if (kt + 2 < 32) OUT_ISSUE(kt + 2)
    int b = kt % 3;
    half8 af[4], bf[2];
#pragma unroll
    for (int mt = 0; mt < 4; ++mt)
      af[mt] = *(const half8*)&As[b][(wm + mt * 16 + c) * 32 + ((quad ^ csw) * 8)];
#pragma unroll
    for (int nt = 0; nt < 2; ++nt)
      bf[nt] = *(const half8*)&Bs[b][(wn + nt * 16 + c) * 32 + ((quad ^ csw) * 8)];
#pragma unroll
    for (int mt = 0; mt < 4; ++mt)
#pragma unroll
      for (int nt = 0; nt < 2; ++nt)
        acc[mt][nt] = MFMA32K(af[mt], bf[nt], acc[mt][nt]);
  }
#undef OUT_ISSUE

#pragma unroll
  for (int nt = 0; nt < 2; ++nt) {
    int n = n0 + wn + nt * 16 + c;
    float bv = bias[n];
#pragma unroll
    for (int mt = 0; mt < 4; ++mt)
#pragma unroll
      for (int r = 0; r < 4; ++r) {
        int m = m0 + wm + mt * 16 + quad * 4 + r;
        outf[(size_t)m * 1024 + n] = acc[mt][nt][r] + bv;
      }
  }
}

// ---------------- masked flash attention (r8 body + mask LUT) ---------------
__global__ __launch_bounds__(512) void attn_kernel(
    const half_t* __restrict__ qb, const half_t* __restrict__ kb,
    const half_t* __restrict__ vTg, half_t* __restrict__ ctx,
    const uint64_t* __restrict__ maskw, const uint8_t* __restrict__ tok,
    const uint8_t* __restrict__ tok16g) {
  __shared__ half_t kT[64 * 64];
  __shared__ half_t vT[64 * 64];
  __shared__ half_t ot[128 * 72];
  __shared__ int list[34];
  __shared__ uint8_t tok16s[256];
  __shared__ uint32_t mlut[16][2];

  int tid = threadIdx.x, wave = tid >> 6, lane = tid & 63;
  int c = lane & 15, q = lane >> 4;
  int id = blockIdx.x;
  int bh = (id & 7) * 4 + ((id >> 3) & 3);  // XCD-major: bh fixed per XCD
  int it128 = id >> 5;
  int i0 = it128 << 7;
  const half_t* qbase = qb + (size_t)bh * SEQ * HD;
  const half_t* kg = kb + (size_t)bh * SEQ * HD;
  const half_t* vg = vTg + (size_t)bh * HD * SEQ;

  if (tid < 256) tok16s[tid] = tok16g[tid];
  if (tid >= 256 && tid < 272) {
    int t = tid - 256;
    mlut[t][0] = (t & 1 ? 0xFFFFu : 0u) | (t & 2 ? 0xFFFF0000u : 0u);
    mlut[t][1] = (t & 4 ? 0xFFFFu : 0u) | (t & 8 ? 0xFFFF0000u : 0u);
  }
  if (wave == 0) {
    int jt = lane;
    int base = i0 >> 6;
    bool act = (jt < 32) &&
               (tok[(jt - base) + 32] | tok[(jt - base - 1) + 32]);
    unsigned long long bal = __ballot(act);
    if (act) {
      int pre = __popcll(bal & ((1ull << jt) - 1));
      list[1 + pre] = jt << 6;
    }
    if (lane == 0) list[0] = __popcll(bal);
  }

  int i_row = i0 + wave * 16 + c;
  int it16 = (i0 >> 4) + wave;
  half8 qf0 = *(const half8*)(qbase + (size_t)i_row * 64 + q * 8);
  half8 qf1 = *(const half8*)(qbase + (size_t)i_row * 64 + 32 + q * 8);

  floatx4 oacc[4] = {};
  floatx4 lacc = {};
  half4 ones;
  ones[0] = (half_t)1.f; ones[1] = (half_t)1.f;
  ones[2] = (half_t)1.f; ones[3] = (half_t)1.f;

  int srow = tid >> 3;      // 0..63
  int sch = tid & 7;        // 0..7
  int ssw = srow & 7;

  __syncthreads();  // list + tok16s + mlut ready
  int nact = list[0];
  int j0 = list[1];

  half8 kr = *(const half8*)(kg + (size_t)(j0 + srow) * 64 + sch * 8);
  half8 vr = *(const half8*)(vg + (size_t)srow * SEQ + j0 + sch * 8);
  uint64_t wcur = maskw[(i_row - j0) + 2048];

  for (int ti = 0; ti < nact; ++ti) {
    int bidx = (j0 >> 4) - it16 + 128;
    __syncthreads();  // A: previous compute done
    *(half8*)&kT[srow * 64 + ((sch ^ ssw) * 8)] = kr;
    *(half8*)&vT[srow * 64 + ((sch ^ ssw) * 8)] = vr;
    int j0n = (ti + 1 < nact) ? list[2 + ti] : j0;
    __syncthreads();  // B: ds_writes visible

    // T14: issue next-tile loads AFTER the barrier
    uint64_t wnext = wcur;
    if (ti + 1 < nact) {
      kr = *(const half8*)(kg + (size_t)(j0n + srow) * 64 + sch * 8);
      vr = *(const half8*)(vg + (size_t)srow * SEQ + j0n + sch * 8);
      wnext = maskw[(i_row - j0n) + 2048];
    }

    uint32_t wlo = (uint32_t)(wcur >> (4 * q));
    uint32_t whi = (uint32_t)(wcur >> (32 + 4 * q));
    uint32x2 mm[4];
#pragma unroll
    for (int jt = 0; jt < 4; ++jt) {
      uint32_t ww = (jt < 2) ? wlo : whi;
      uint32_t nib = (ww >> (16 * (jt & 1))) & 15u;
      mm[jt] = *(const uint32x2*)&mlut[nib][0];
    }
#pragma unroll
    for (int jt = 0; jt < 4; ++jt) {
      if (!tok16s[bidx + jt]) continue;  // wave-uniform subtile skip
      int row = jt * 16 + c;
      int sw = c & 7;
      half8 a0 = *(const half8*)&kT[row * 64 + ((q ^ sw) * 8)];
      half8 a1 = *(const half8*)&kT[row * 64 + (((4 + q) ^ sw) * 8)];
      floatx4 t = {};
      t = MFMA32K(a0, qf0, t);
      t = MFMA32K(a1, qf1, t);
      float p0 = __builtin_exp2f(t[0]);
      float p1 = __builtin_exp2f(t[1]);
      float p2 = __builtin_exp2f(t[2]);
      float p3 = __builtin_exp2f(t[3]);
      auto lo = __builtin_amdgcn_cvt_pkrtz(p0, p1);
      auto hi = __builtin_amdgcn_cvt_pkrtz(p2, p3);
      union { uint32_t u[2]; half4 h4; } pu;
      pu.u[0] = __builtin_bit_cast(uint32_t, lo) & mm[jt][0];
      pu.u[1] = __builtin_bit_cast(uint32_t, hi) & mm[jt][1];
      half4 pb = pu.h4;
      lacc = MFMA16(ones, pb, lacc);
#pragma unroll
      for (int mt = 0; mt < 4; ++mt) {
        int drow = mt * 16 + c;
        int ch = 2 * jt + (q >> 1);
        half4 a = *(const half4*)&vT[drow * 64 + ((ch ^ sw) * 8) + (q & 1) * 4];
        oacc[mt] = MFMA16(a, pb, oacc[mt]);
      }
    }
    wcur = wnext;
    j0 = j0n;
  }

  // epilogue: normalize, transpose via LDS, coalesced ctx write
  float inv_l = 1.0f / lacc[0];
#pragma unroll
  for (int mt = 0; mt < 4; ++mt)
#pragma unroll
    for (int r = 0; r < 4; ++r)
      ot[(wave * 16 + c) * 72 + mt * 16 + 4 * q + r] = (half_t)(oacc[mt][r] * inv_l);
  __syncthreads();
  {
    int row = tid >> 2, chq = tid & 3;  // 128 rows x 4 chunk-pairs
    int b = bh >> 4, h = bh & 15;
    size_t base = (((size_t)(b * SEQ + i0 + row) * NH) + h) * 64 + chq * 16;
    half8 v0 = *(const half8*)&ot[row * 72 + chq * 16];
    half8 v1 = *(const half8*)&ot[row * 72 + chq * 16 + 8];
    *(half8*)(ctx + base) = v0;
    *(half8*)(ctx + base + 8) = v1;
  }
}

// ---------------- launch -----------------------------------------------------
extern "C" void kernel_launch(void* const* d_in, const int* in_sizes, int n_in,
                              void* d_out, int out_size, void* d_ws, size_t ws_size,
                              hipStream_t stream) {
  const float* query = (const float*)d_in[0];
  const float* key_value = (const float*)d_in[1];
  const float* Wq = (const float*)d_in[2];
  const float* bq = (const float*)d_in[3];
  const float* Wkv = (const float*)d_in[4];
  const float* bkv = (const float*)d_in[5];
  const float* Wo = (const float*)d_in[6];
  const float* bo = (const float*)d_in[7];

  char* ws = (char*)d_ws;
  uint8_t* tok = (uint8_t*)ws;               // 64
  uint8_t* tok16 = (uint8_t*)(ws + 1024);    // 256
  uint64_t* maskw = (uint64_t*)(ws + 4096);  // 32KB
  const size_t MB = 1ull << 20;
  half_t* xq = (half_t*)(ws + 1 * MB);    // 8MB; reused as ctx after qkv gemm
  half_t* xkv = (half_t*)(ws + 9 * MB);   // 8MB
  half_t* wqT = (half_t*)(ws + 17 * MB);  // 2MB
  half_t* wkvT = (half_t*)(ws + 19 * MB); // 4MB
  half_t* woT = (half_t*)(ws + 23 * MB);  // 2MB
  half_t* qbuf = (half_t*)(ws + 25 * MB); // 8MB
  half_t* kbuf = (half_t*)(ws + 33 * MB); // 8MB
  half_t* vTg = (half_t*)(ws + 41 * MB);  // 8MB ([bh][d][s])
  half_t* ctx = xq;                       // alias (xq dead after proj)

  hipLaunchKernelGGL(prep, dim3(4112), dim3(256), 0, stream,
                     query, key_value, Wq, Wkv, Wo, xq, xkv, wqT, wkvT, woT,
                     tok, tok16, maskw);
  hipLaunchKernelGGL(gemm_qkv, dim3(16, 12), dim3(512), 131072, stream,
                     xq, xkv, wqT, wkvT, bq, bkv, qbuf, kbuf, vTg);
  hipLaunchKernelGGL(attn_kernel, dim3(512), dim3(512), 0, stream,
                     qbuf, kbuf, vTg, ctx, maskw, tok, tok16);
  hipLaunchKernelGGL(gemm_out, dim3(32, 16), dim3(256), 0, stream,
                     ctx, woT, bo, (float*)d_out);
}